// Round 12
// baseline (103.056 us; speedup 1.0000x reference)
//
#include <hip/hip_runtime.h>
#include <stdint.h>

#define NAG 4096
#define TOPK 12
#define EPSF 1e-4f
#define NT 512
#define WPB 8               // waves (=agents) per block
#define NBLK (NAG / WPB)    // 512 blocks
#define MTOT (NAG * TOPK)   // 49152 rows

typedef unsigned long long u64;
typedef short short8v __attribute__((ext_vector_type(8)));
typedef float f32x4 __attribute__((ext_vector_type(4)));

// round-to-nearest-even f32 -> bf16 bits
__device__ __forceinline__ unsigned short f2bf(float f) {
    union { float f; unsigned u; } v; v.f = f;
    unsigned r = v.u + 0x7FFFu + ((v.u >> 16) & 1u);
    return (unsigned short)(r >> 16);
}

// One DPP stage of a 64-lane (hi,lo) u64-min reduction (validated R5-R8).
template <int CTRL>
__device__ __forceinline__ void dpp_min_step(unsigned &hi, unsigned &lo) {
    unsigned ohi = (unsigned)__builtin_amdgcn_update_dpp((int)hi, (int)hi, CTRL, 0xf, 0xf, false);
    unsigned olo = (unsigned)__builtin_amdgcn_update_dpp((int)lo, (int)lo, CTRL, 0xf, 0xf, false);
    bool t = (ohi < hi) || (ohi == hi && olo < lo);
    hi = t ? ohi : hi;
    lo = t ? olo : lo;
}

// ======= Kernel 0: preconvert W2,W3 -> bf16 (Wb[0:8192]=W2, Wb[8192:16384]=W3)
__global__ __launch_bounds__(256)
void cbf_prep(const float* __restrict__ W2, const float* __restrict__ W3,
              unsigned short* __restrict__ Wb) {
    int idx = blockIdx.x * 256 + threadIdx.x;          // 64 blocks x 256 = 16384
    float v = (idx < 8192) ? W2[idx] : W3[idx - 8192];
    Wb[idx] = f2bf(v);
}

// ======= Kernel 1: wave-per-agent FUSED select + MFMA MLP =======
// 512 blocks x 512 threads; wave wv owns agent i = blk*8+wv end-to-end.
// One __syncthreads total (after xy->LDS stage); all else wave-local.
// Selection: T = 12th-smallest of 64 per-lane mins (upper bound on true d12),
// ballot-compact survivors (E[cnt]~13), exact u64-key rank-select
// (key order == lax.top_k order). Numerics bit-exact f32 (no contraction,
// rn sqrt). MLP: L1 f32 -> A-frags in REGISTERS, L2/L3 MFMA bf16 (R8
// layouts verbatim), L4 f32 shfl-reduce.
__global__ __launch_bounds__(NT, 4)
void cbf_fused(const float* __restrict__ states,
               const float* __restrict__ W1, const float* __restrict__ b1,
               const unsigned short* __restrict__ Wb,   // W2bf | W3bf
               const float* __restrict__ b2, const float* __restrict__ b3,
               const float* __restrict__ W4, const float* __restrict__ b4,
               float* __restrict__ out)
{
    const int t = threadIdx.x;
    const int lane = t & 63;
    const int wv = t >> 6;
    const int i = blockIdx.x * WPB + wv;    // agent

    __shared__ float2 s_xy[NAG];                              // 32 KB
    __shared__ u64 s_surv[WPB][64];                           // 4 KB
    __shared__ int s_sel[WPB][TOPK];
    __shared__ float s_x[WPB][72];                            // flat72 per agent
    __shared__ float s_mask[WPB][TOPK];
    __shared__ __align__(16) unsigned char s_h2[WPB][4096];   // 32 KB

    // ---- Stage: xy -> LDS (coalesced float4 reads, discard zw)
#pragma unroll
    for (int u = 0; u < 8; ++u) {
        int r = u * NT + t;
        float4 sr = reinterpret_cast<const float4*>(states)[r];
        s_xy[r] = make_float2(sr.x, sr.y);
    }
    __syncthreads();   // the ONLY block barrier

    const float2 sif = s_xy[i];   // exact copy of states[i][0..1]
    const float si0 = sif.x, si1 = sif.y;

    // ---- Pass A: per-lane min over 64 candidates (bit-exact f32)
    unsigned minb = 0xFFFFFFFFu;
    int minj = 0;
#pragma unroll 8
    for (int u = 0; u < 64; ++u) {
        float2 sj = s_xy[u * 64 + lane];
        float dx0 = __fsub_rn(si0, sj.x);
        float dx1 = __fsub_rn(si1, sj.y);
        float d2 = __fadd_rn(__fadd_rn(__fmul_rn(dx0, dx0), EPSF),
                             __fadd_rn(__fmul_rn(dx1, dx1), EPSF));
        unsigned b = __float_as_uint(__fsqrt_rn(d2));  // positive: bit order == value order
        if (b < minb) { minb = b; minj = u * 64 + lane; }  // strict <: lowest j on tie
    }

    // ---- T-find: 12th-smallest lane-min key via 12 static DPP rounds
    unsigned Tb;
    {
        unsigned khi = minb, klo = (unsigned)minj;
        unsigned Tcur = 0;
        for (int r = 0; r < TOPK; ++r) {
            unsigned hi = khi, lo = klo;
            dpp_min_step<0xB1>(hi, lo);    // quad_perm xor1
            dpp_min_step<0x4E>(hi, lo);    // quad_perm xor2
            dpp_min_step<0x124>(hi, lo);   // row_ror:4
            dpp_min_step<0x128>(hi, lo);   // row_ror:8
            dpp_min_step<0x142>(hi, lo);   // row_bcast15
            dpp_min_step<0x143>(hi, lo);   // row_bcast31
            unsigned hw = (unsigned)__builtin_amdgcn_readlane((int)hi, 63);
            unsigned lw = (unsigned)__builtin_amdgcn_readlane((int)lo, 63);
            Tcur = hw;
            if (khi == hw && klo == lw) khi = 0xFFFFFFFFu;   // mask unique winner
        }
        Tb = Tcur;
    }

    // ---- Pass B: recompute + ballot-compact survivors (dn <= T); >=12 guaranteed
    int cnt = 0;
#pragma unroll 8
    for (int u = 0; u < 64; ++u) {
        float2 sj = s_xy[u * 64 + lane];
        float dx0 = __fsub_rn(si0, sj.x);
        float dx1 = __fsub_rn(si1, sj.y);
        float d2 = __fadd_rn(__fadd_rn(__fmul_rn(dx0, dx0), EPSF),
                             __fadd_rn(__fmul_rn(dx1, dx1), EPSF));
        unsigned b = __float_as_uint(__fsqrt_rn(d2));
        bool p = (b <= Tb);
        u64 mk = __ballot(p);
        if (p) {
            int pos = cnt + __popcll(mk & ((1ull << lane) - 1ull));
            if (pos < 64)
                s_surv[wv][pos] = ((u64)b << 32) | (unsigned)(u * 64 + lane);
        }
        cnt += __popcll(mk);
    }
    if (cnt > 64) cnt = 64;
    __asm volatile("s_waitcnt lgkmcnt(0)" ::: "memory");
    __builtin_amdgcn_wave_barrier();

    // ---- Rank-select (key order == lax.top_k order)
    if (lane < cnt) {
        u64 kA = s_surv[wv][lane];
        int rA = 0;
        for (int q = 0; q < cnt; ++q)
            rA += (s_surv[wv][q] < kA) ? 1 : 0;     // uniform addr -> broadcast
        if (rA < TOPK) s_sel[wv][rA] = (int)(unsigned)(kA & 0xffffffffull);
    }
    __asm volatile("s_waitcnt lgkmcnt(0)" ::: "memory");
    __builtin_amdgcn_wave_barrier();

    // ---- flat72 + mask
    if (lane < TOPK) {
        int j = s_sel[wv][lane];
        const float4 sj = reinterpret_cast<const float4*>(states)[j];
        const float4 si = reinterpret_cast<const float4*>(states)[i];
        float dx0 = __fsub_rn(si.x, sj.x);
        float dx1 = __fsub_rn(si.y, sj.y);
        float dx2 = __fsub_rn(si.z, sj.z);
        float dx3 = __fsub_rn(si.w, sj.w);
        float d2 = __fadd_rn(__fadd_rn(__fmul_rn(dx0, dx0), EPSF),
                             __fadd_rn(__fmul_rn(dx1, dx1), EPSF));
        float dn = __fsqrt_rn(d2);
        s_x[wv][lane * 6 + 0] = dx0;
        s_x[wv][lane * 6 + 1] = dx1;
        s_x[wv][lane * 6 + 2] = dx2;
        s_x[wv][lane * 6 + 3] = dx3;
        s_x[wv][lane * 6 + 4] = (j == i) ? 1.0f : 0.0f;
        s_x[wv][lane * 6 + 5] = __fsub_rn(dn, 0.8f);
        float mk = (dn <= 1.0f) ? 1.0f : 0.0f;
        s_mask[wv][lane] = mk;
        out[MTOT + i * TOPK + lane] = mk;
    }
    __asm volatile("s_waitcnt lgkmcnt(0)" ::: "memory");
    __builtin_amdgcn_wave_barrier();

    // ---- MLP (per wave; 16-row tile, rows 12..15 zeroed) ----
    const int r16 = lane & 15;      // M row (L1/A) / D col (B) index
    const int hi = lane >> 4;       // 0..3

    // L1 (f32): scrambled input xc[ch] = flat72[ch*12 + r16].
    // A-frag in REGISTERS: lane (r16,hi) computes h1[r16][o] for
    // o = 8hi+e (a0[e], k=0..31) and o = 32+8hi+e (a1[e], k=32..63).
    float xc[6];
#pragma unroll
    for (int ch = 0; ch < 6; ++ch)
        xc[ch] = (r16 < TOPK) ? s_x[wv][ch * TOPK + r16] : 0.0f;

    short8v a0, a1;
#pragma unroll
    for (int e = 0; e < 8; ++e) {
        {
            int o = 8 * hi + e;
            const float2* wr = reinterpret_cast<const float2*>(W1 + o * 6);
            float2 w0 = wr[0], w1 = wr[1], w2 = wr[2];
            float acc = b1[o];
            acc = fmaf(w0.x, xc[0], acc);
            acc = fmaf(w0.y, xc[1], acc);
            acc = fmaf(w1.x, xc[2], acc);
            acc = fmaf(w1.y, xc[3], acc);
            acc = fmaf(w2.x, xc[4], acc);
            acc = fmaf(w2.y, xc[5], acc);
            a0[e] = (r16 < TOPK) ? (short)f2bf(fmaxf(acc, 0.0f)) : (short)0;
        }
        {
            int o = 32 + 8 * hi + e;
            const float2* wr = reinterpret_cast<const float2*>(W1 + o * 6);
            float2 w0 = wr[0], w1 = wr[1], w2 = wr[2];
            float acc = b1[o];
            acc = fmaf(w0.x, xc[0], acc);
            acc = fmaf(w0.y, xc[1], acc);
            acc = fmaf(w1.x, xc[2], acc);
            acc = fmaf(w1.y, xc[3], acc);
            acc = fmaf(w2.x, xc[4], acc);
            acc = fmaf(w2.y, xc[5], acc);
            a1[e] = (r16 < TOPK) ? (short)f2bf(fmaxf(acc, 0.0f)) : (short)0;
        }
    }

    unsigned char* lp2 = s_h2[wv];
    const int c = r16;   // D/B column within tile

    // L2 (MFMA): h2 = relu(h1 @ W2^T + b2), 128 cols; W2bf = Wb[0:8192]
#pragma unroll
    for (int nt = 0; nt < 8; ++nt) {
        int o = nt * 16 + c;
        short8v bf0 = *(const short8v*)(Wb + o * 64 + 8 * hi);
        short8v bf1 = *(const short8v*)(Wb + o * 64 + 32 + 8 * hi);
        float bb = b2[o];
        f32x4 acc = {bb, bb, bb, bb};
        acc = __builtin_amdgcn_mfma_f32_16x16x32_bf16(a0, bf0, acc, 0, 0, 0);
        acc = __builtin_amdgcn_mfma_f32_16x16x32_bf16(a1, bf1, acc, 0, 0, 0);
#pragma unroll
        for (int e = 0; e < 4; ++e) {
            unsigned short hv = f2bf(fmaxf(acc[e], 0.0f));
            int mr = 4 * hi + e;                    // D row
            int slot = (2 * nt + (c >> 3)) ^ (mr & 15);
            *(unsigned short*)(lp2 + mr * 256 + slot * 16 + ((2 * c) & 15)) = hv;
        }
    }
    __asm volatile("s_waitcnt lgkmcnt(0)" ::: "memory");
    __builtin_amdgcn_wave_barrier();

    // L3 (MFMA): h3 = relu(h2 @ W3^T + b3), 64 cols; W3bf = Wb[8192:]
    short8v a3[4];
#pragma unroll
    for (int ks = 0; ks < 4; ++ks)
        a3[ks] = *(short8v*)(lp2 + r16 * 256 + (((4 * ks + hi) ^ r16) * 16));
    float h3r[4][4];
#pragma unroll
    for (int nt = 0; nt < 4; ++nt) {
        int o = nt * 16 + c;
        float bb = b3[o];
        f32x4 ac = {bb, bb, bb, bb};
#pragma unroll
        for (int ks = 0; ks < 4; ++ks) {
            short8v bf = *(const short8v*)(Wb + 8192 + o * 128 + ks * 32 + 8 * hi);
            ac = __builtin_amdgcn_mfma_f32_16x16x32_bf16(a3[ks], bf, ac, 0, 0, 0);
        }
#pragma unroll
        for (int e = 0; e < 4; ++e) h3r[nt][e] = fmaxf(ac[e], 0.0f);
    }

    // L4 (f32): out[m] = (h3 . W4 + b4) * mask; reduce over the 16 c-lanes
    float w4c[4];
#pragma unroll
    for (int nt = 0; nt < 4; ++nt) w4c[nt] = W4[nt * 16 + c];
    float part[4];
#pragma unroll
    for (int e = 0; e < 4; ++e) {
        float p = h3r[0][e] * w4c[0];
        p = fmaf(h3r[1][e], w4c[1], p);
        p = fmaf(h3r[2][e], w4c[2], p);
        p = fmaf(h3r[3][e], w4c[3], p);
        part[e] = p;
    }
#pragma unroll
    for (int off = 1; off <= 8; off <<= 1) {
#pragma unroll
        for (int e = 0; e < 4; ++e)
            part[e] += __shfl_xor(part[e], off, 64);
    }
    if (c == 0) {
        float bb4 = b4[0];
#pragma unroll
        for (int e = 0; e < 4; ++e) {
            int mr = 4 * hi + e;
            if (mr < TOPK)
                out[i * TOPK + mr] = (part[e] + bb4) * s_mask[wv][mr];
        }
    }
}

extern "C" void kernel_launch(void* const* d_in, const int* in_sizes, int n_in,
                              void* d_out, int out_size, void* d_ws, size_t ws_size,
                              hipStream_t stream) {
    const float* states = (const float*)d_in[0];
    const float* W1 = (const float*)d_in[1];
    const float* b1 = (const float*)d_in[2];
    const float* W2 = (const float*)d_in[3];
    const float* b2 = (const float*)d_in[4];
    const float* W3 = (const float*)d_in[5];
    const float* b3 = (const float*)d_in[6];
    const float* W4 = (const float*)d_in[7];
    const float* b4 = (const float*)d_in[8];
    float* out = (float*)d_out;
    unsigned short* Wb = (unsigned short*)d_ws;   // 16384 bf16 = 32 KB

    cbf_prep<<<dim3(64), dim3(256), 0, stream>>>(W2, W3, Wb);
    cbf_fused<<<dim3(NBLK), dim3(NT), 0, stream>>>(states, W1, b1, Wb,
                                                   b2, b3, W4, b4, out);
}